// Round 1
// baseline (864.507 us; speedup 1.0000x reference)
//
#include <hip/hip_runtime.h>
#include <math.h>

#define BATCH 8
#define N 4096
#define KNN 20
#define H 64
#define P_TOT (BATCH * N)          // 32768 points
#define EDGES (P_TOT * KNN)        // 655360 edges
#define NB1 512                    // stats blocks
#define EPB (EDGES / NB1)          // 1280 edges per stats block
#define BN_EPS 1e-5
#define NEG_SLOPE 0.2f

// ---------- helpers ----------
__device__ __forceinline__ unsigned int fkey(float f) {
    // monotonic transform: float order -> unsigned order
    unsigned int u = __float_as_uint(f);
    return (u & 0x80000000u) ? ~u : (u | 0x80000000u);
}
__device__ __forceinline__ unsigned long long umin64(unsigned long long a, unsigned long long b) {
    return a < b ? a : b;
}

// ---------- kernel 1: SoA pack + |p|^2 ----------
__global__ __launch_bounds__(256) void soa_pack(const float* __restrict__ pcd, float* __restrict__ ws) {
    int i = blockIdx.x * 256 + threadIdx.x;   // global point id
    float x = pcd[i * 3 + 0];
    float y = pcd[i * 3 + 1];
    float z = pcd[i * 3 + 2];
    // sq = (x*x + y*y) + z*z, IEEE rn, no contraction (must match ref bit-exact)
    float sq = __fadd_rn(__fadd_rn(__fmul_rn(x, x), __fmul_rn(y, y)), __fmul_rn(z, z));
    ws[i] = x;
    ws[P_TOT + i] = y;
    ws[2 * P_TOT + i] = z;
    ws[3 * P_TOT + i] = sq;
}

// ---------- kernel 2: kNN (top-20 smallest d2, ties -> lower index) ----------
// One block of 256 threads handles 4 consecutive query points.
// Thread t owns candidates m = j*256 + t (j=0..15), distances kept in registers.
__global__ __launch_bounds__(256) void knn_kernel(const float* __restrict__ ws, int* __restrict__ idx_out) {
    __shared__ unsigned long long keys[256];
    __shared__ unsigned long long bcast;

    const int t = threadIdx.x;
    const int qbase = blockIdx.x * 4;       // global point id of first query
    const int base = qbase & ~(N - 1);      // batch base (b*N); 4 queries same batch

    const float* xs = ws;
    const float* ys = ws + P_TOT;
    const float* zs = ws + 2 * P_TOT;
    const float* ss = ws + 3 * P_TOT;

    float qx[4], qy[4], qz[4], qs[4];
#pragma unroll
    for (int q = 0; q < 4; ++q) {
        int gp = qbase + q;
        qx[q] = xs[gp]; qy[q] = ys[gp]; qz[q] = zs[gp]; qs[q] = ss[gp];
    }

    float d[4][16];
    float dmin[4];
    int mmin[4];
#pragma unroll
    for (int q = 0; q < 4; ++q) { dmin[q] = INFINITY; mmin[q] = 0; }

#pragma unroll
    for (int j = 0; j < 16; ++j) {
        const int m = j * 256 + t;
        const int g = base + m;
        const float xm = xs[g], ym = ys[g], zm = zs[g], sm = ss[g];
#pragma unroll
        for (int q = 0; q < 4; ++q) {
            // dot = ((qx*xm + qy*ym) + qz*zm); d2 = (sq_q + sq_m) - 2*dot — all rn, no fma
            float dot = __fadd_rn(__fadd_rn(__fmul_rn(qx[q], xm), __fmul_rn(qy[q], ym)),
                                  __fmul_rn(qz[q], zm));
            float dd = __fsub_rn(__fadd_rn(qs[q], sm), __fmul_rn(2.0f, dot));
            d[q][j] = dd;
            if (dd < dmin[q]) { dmin[q] = dd; mmin[q] = m; }   // j asc => lowest m on tie
        }
    }

    unsigned int mask[4] = {0u, 0u, 0u, 0u};

#pragma unroll
    for (int q = 0; q < 4; ++q) {
        keys[t] = ((unsigned long long)fkey(dmin[q]) << 32) | (unsigned int)mmin[q];
        __syncthreads();
        for (int p = 0; p < KNN; ++p) {
            if (t < 64) {
                unsigned long long k0 = keys[t];
                k0 = umin64(k0, keys[t + 64]);
                k0 = umin64(k0, keys[t + 128]);
                k0 = umin64(k0, keys[t + 192]);
#pragma unroll
                for (int off = 32; off; off >>= 1) {
                    unsigned long long o = __shfl_xor(k0, off);
                    k0 = umin64(k0, o);
                }
                if (t == 0) {
                    bcast = k0;
                    idx_out[(qbase + q) * KNN + p] = (int)(k0 & 0xFFFFFFFFull);
                }
            }
            __syncthreads();
            const unsigned long long w = bcast;
            const int mw = (int)(w & 0xFFFFFFFFull);
            if ((mw & 255) == t) {
                const int slot = mw >> 8;
                mask[q] |= (1u << slot);
                float dm = INFINITY;
                int mm = 0;
#pragma unroll
                for (int j = 0; j < 16; ++j) {
                    float dd = ((mask[q] >> j) & 1u) ? INFINITY : d[q][j];
                    if (dd < dm) { dm = dd; mm = j * 256 + t; }
                }
                dmin[q] = dm; mmin[q] = mm;
                keys[t] = ((unsigned long long)fkey(dm) << 32) | (unsigned int)mm;
            }
            __syncthreads();
        }
    }
}

// ---------- kernel 3: BN statistics (sum, sumsq per channel), deterministic ----------
// block = 256 = 4 edge-groups x 64 channels; per-block partials to ws
__global__ __launch_bounds__(256) void stats_kernel(const float* __restrict__ ws,
                                                    const int* __restrict__ idx,
                                                    const float* __restrict__ W,
                                                    const float* __restrict__ bias,
                                                    float* __restrict__ partials) {
    const int t = threadIdx.x;
    const int c = t & 63;
    const int g = t >> 6;

    float wcol[6];
#pragma unroll
    for (int f = 0; f < 6; ++f) wcol[f] = W[f * H + c];
    const float bc = bias[c];

    const float* xs = ws;
    const float* ys = ws + P_TOT;
    const float* zs = ws + 2 * P_TOT;

    float sum = 0.f, sq = 0.f;
    const int e0 = blockIdx.x * EPB;
    for (int i = g; i < EPB; i += 4) {
        const int e = e0 + i;
        const int gp = e / KNN;              // global point id
        const int gb = gp & ~(N - 1);        // batch base
        const int m = idx[e];
        const int gj = gb + m;
        const float xj = xs[gj], yj = ys[gj], zj = zs[gj];
        const float xi = xs[gp], yi = ys[gp], zi = zs[gp];
        float h = bc;
        h = fmaf(wcol[0], xj, h);
        h = fmaf(wcol[1], yj, h);
        h = fmaf(wcol[2], zj, h);
        h = fmaf(wcol[3], xi - xj, h);
        h = fmaf(wcol[4], yi - yj, h);
        h = fmaf(wcol[5], zi - zj, h);
        sum += h;
        sq = fmaf(h, h, sq);
    }

    __shared__ float ls[4][64];
    __shared__ float lq[4][64];
    ls[g][c] = sum;
    lq[g][c] = sq;
    __syncthreads();
    if (t < 64) {
        float s = ls[0][t] + ls[1][t] + ls[2][t] + ls[3][t];
        float qq = lq[0][t] + lq[1][t] + lq[2][t] + lq[3][t];
        partials[blockIdx.x * 128 + t] = s;
        partials[blockIdx.x * 128 + 64 + t] = qq;
    }
}

// ---------- kernel 4: finalize BN, fold affine into W2/bias2 ----------
__global__ void finalize_kernel(const float* __restrict__ partials,
                                const float* __restrict__ W,
                                const float* __restrict__ bias,
                                const float* __restrict__ gamma,
                                const float* __restrict__ beta,
                                float* __restrict__ w2) {
    const int c = threadIdx.x;   // 64 threads
    double s = 0.0, q = 0.0;
    for (int i = 0; i < NB1; ++i) {
        s += (double)partials[i * 128 + c];
        q += (double)partials[i * 128 + 64 + c];
    }
    const double cnt = (double)EDGES;
    const double mean = s / cnt;
    const double var = q / cnt - mean * mean;
    const double a = (double)gamma[c] / sqrt(var + BN_EPS);
    const float af = (float)a;
    const float b2 = (float)((double)beta[c] - mean * a);
#pragma unroll
    for (int f = 0; f < 6; ++f) w2[f * H + c] = W[f * H + c] * af;
    w2[6 * H + c] = fmaf(bias[c], af, b2);
}

// ---------- kernel 5: edge MLP + LeakyReLU + max-pool over K ----------
// wave = 64 channels of one point; block = 4 points
__global__ __launch_bounds__(256) void out_kernel(const float* __restrict__ ws,
                                                  const int* __restrict__ idx,
                                                  const float* __restrict__ w2,
                                                  float* __restrict__ out) {
    const int t = threadIdx.x;
    const int c = t & 63;
    const int gp = blockIdx.x * 4 + (t >> 6);
    const int gb = gp & ~(N - 1);

    const float* xs = ws;
    const float* ys = ws + P_TOT;
    const float* zs = ws + 2 * P_TOT;

    float wcol[6];
#pragma unroll
    for (int f = 0; f < 6; ++f) wcol[f] = w2[f * H + c];
    const float bc = w2[6 * H + c];

    const float xi = xs[gp], yi = ys[gp], zi = zs[gp];

    float vmax = -INFINITY;
    for (int k = 0; k < KNN; ++k) {
        const int m = idx[gp * KNN + k];
        const int gj = gb + m;
        const float xj = xs[gj], yj = ys[gj], zj = zs[gj];
        float h = bc;
        h = fmaf(wcol[0], xj, h);
        h = fmaf(wcol[1], yj, h);
        h = fmaf(wcol[2], zj, h);
        h = fmaf(wcol[3], xi - xj, h);
        h = fmaf(wcol[4], yi - yj, h);
        h = fmaf(wcol[5], zi - zj, h);
        h = (h >= 0.f) ? h : NEG_SLOPE * h;
        vmax = fmaxf(vmax, h);
    }
    out[gp * H + c] = vmax;
}

extern "C" void kernel_launch(void* const* d_in, const int* in_sizes, int n_in,
                              void* d_out, int out_size, void* d_ws, size_t ws_size,
                              hipStream_t stream) {
    const float* pcd   = (const float*)d_in[0];
    const float* W     = (const float*)d_in[1];
    const float* bias  = (const float*)d_in[2];
    const float* gamma = (const float*)d_in[3];
    const float* beta  = (const float*)d_in[4];

    float* wsf      = (float*)d_ws;
    float* soa      = wsf;                              // 4*P_TOT floats
    int*   idx      = (int*)(wsf + 4 * P_TOT);          // EDGES ints
    float* partials = wsf + 4 * P_TOT + EDGES;          // NB1*128 floats
    float* w2       = partials + NB1 * 128;             // 7*64 floats
    float* out      = (float*)d_out;

    soa_pack<<<P_TOT / 256, 256, 0, stream>>>(pcd, soa);
    knn_kernel<<<P_TOT / 4, 256, 0, stream>>>(soa, idx);
    stats_kernel<<<NB1, 256, 0, stream>>>(soa, idx, W, bias, partials);
    finalize_kernel<<<1, 64, 0, stream>>>(partials, W, bias, gamma, beta, w2);
    out_kernel<<<P_TOT / 4, 256, 0, stream>>>(soa, idx, w2, out);
}

// Round 2
// 828.230 us; speedup vs baseline: 1.0438x; 1.0438x over previous
//
#include <hip/hip_runtime.h>
#include <math.h>

#define KNN 20
#define NPTS 4096
#define BATCH 8
#define P_TOT (BATCH * NPTS)       // 32768
#define QPW 8                      // queries per wave
#define QPB 32                     // queries per block (4 waves)
#define NBLK (P_TOT / QPB)         // 1024 blocks
#define BPB (NPTS / QPB)           // 128 blocks per batch
#define BN_EPS 1e-5
#define NEG_SLOPE 0.2f

// float-offsets into ws
#define FO_CLOUD 0                 // 32768 float4 = 131072 floats
#define FO_PART  131072            // 4096 wave-partials x 128 floats = 524288
#define FO_AB    655360            // 128 floats (a, shift)
#define FO_W2    655488            // 448 floats (folded W + bias)
#define FO_BIG   655936            // rawmin (2097152 f) or idx (655360 i)

// ---------- kernel 1: pack cloud as float4 (x,y,z,|p|^2) ----------
__global__ __launch_bounds__(256) void pack_kernel(const float* __restrict__ pcd,
                                                   float4* __restrict__ cloud) {
    int i = blockIdx.x * 256 + threadIdx.x;
    float x = pcd[3 * i], y = pcd[3 * i + 1], z = pcd[3 * i + 2];
    // exact-rn, no contraction: must match reference bit-exactly
    float sq = __fadd_rn(__fadd_rn(__fmul_rn(x, x), __fmul_rn(y, y)), __fmul_rn(z, z));
    cloud[i] = make_float4(x, y, z, sq);
}

// masked group-min recompute (all indices compile-time static)
#define RE_ELEM(G, E) { \
    float cv_ = ((mask >> (8 * (G) + (E))) & 1ull) ? INFINITY : d[8 * (G) + (E)]; \
    if (cv_ < bv_) { bv_ = cv_; bs_ = 8 * (G) + (E); } }
#define RECOMP(G) { \
    float bv_ = ((mask >> (8 * (G))) & 1ull) ? INFINITY : d[8 * (G)]; \
    int bs_ = 8 * (G); \
    RE_ELEM(G, 1) RE_ELEM(G, 2) RE_ELEM(G, 3) RE_ELEM(G, 4) \
    RE_ELEM(G, 5) RE_ELEM(G, 6) RE_ELEM(G, 7) \
    gv[G] = bv_; gs[G] = bs_; }

// ---------- kernel 2: fused kNN + edge-MLP stats + raw max/min ----------
// block = 256 = 4 waves; wave = one query at a time (8 per wave); cloud in LDS.
template <bool FAST>
__global__ __launch_bounds__(256) void knn_kernel(const float4* __restrict__ cloud,
                                                  const float* __restrict__ W,
                                                  const float* __restrict__ bias,
                                                  float* __restrict__ partials,
                                                  float* __restrict__ rawmax,
                                                  float* __restrict__ rawmin,
                                                  int* __restrict__ idxo) {
    __shared__ float4 cl[NPTS];    // 64 KB exactly
    const int t = threadIdx.x;
    const int wave = t >> 6, lane = t & 63;
    const int bidx = blockIdx.x;
    const int batch = bidx >> 7;           // BPB = 128
    const int gbase = batch * NPTS;

    // stage batch cloud into LDS (coalesced float4)
#pragma unroll
    for (int it = 0; it < NPTS / 256; ++it)
        cl[it * 256 + t] = cloud[gbase + it * 256 + t];
    __syncthreads();

    // per-lane (=channel) MLP column for the stats/raw phase
    const float wc0 = W[lane], wc1 = W[64 + lane], wc2 = W[128 + lane];
    const float wc3 = W[192 + lane], wc4 = W[256 + lane], wc5 = W[320 + lane];
    const float bb = bias[lane];
    float se = 0.f, sqs = 0.f;

    for (int qi = 0; qi < QPW; ++qi) {
        const int q = (bidx & (BPB - 1)) * QPB + wave * QPW + qi;  // in-batch query id
        const int gq = gbase + q;
        const float4 Q = cl[q];
        const float qx = Q.x, qy = Q.y, qz = Q.z, qs = Q.w;

        // ---- distance pass: 64 candidates per lane, register-resident ----
        float d[64];
        float gv[8]; int gs[8];
#pragma unroll
        for (int j = 0; j < 64; ++j) {
            const float4 C = cl[j * 64 + lane];
            // identical arithmetic to the validated Round-1 formula
            float dot = __fadd_rn(__fadd_rn(__fmul_rn(qx, C.x), __fmul_rn(qy, C.y)),
                                  __fmul_rn(qz, C.z));
            float dd = __fsub_rn(__fadd_rn(qs, C.w), __fmul_rn(2.0f, dot));
            d[j] = dd;
            const int g = j >> 3;
            if ((j & 7) == 0) { gv[g] = dd; gs[g] = j; }
            else if (dd < gv[g]) { gv[g] = dd; gs[g] = j; }
        }
        float dmin = gv[0]; int smin = gs[0];
#pragma unroll
        for (int g = 1; g < 8; ++g) if (gv[g] < dmin) { dmin = gv[g]; smin = gs[g]; }
        int mmin = smin * 64 + lane;
        unsigned long long mask = 0ull;

        float hmax = -INFINITY, hmin = INFINITY;

        // ---- 20 extract-min picks, barrier-free ----
#pragma unroll 1
        for (int p = 0; p < KNN; ++p) {
            // wave-wide float min
            float g = dmin;
#pragma unroll
            for (int off = 32; off; off >>= 1) g = fminf(g, __shfl_xor(g, off));
            int win;
            unsigned long long bal = __ballot(dmin == g);
            if (__popcll(bal) > 1) {
                // exact tie on distance: smallest global index wins (lax.top_k rule)
                int mv = (dmin == g) ? mmin : 0x7FFFFFFF;
#pragma unroll
                for (int off = 32; off; off >>= 1) mv = min(mv, __shfl_xor(mv, off));
                win = mv;
            } else {
                int owner = __ffsll((unsigned long long)bal) - 1;
                win = __shfl(mmin, owner);
            }

            if (!FAST) { if (lane == 0) idxo[gq * KNN + p] = win; }

            // ---- fused channel phase: lane = channel ----
            const float4 C = cl[win];                 // broadcast
            float raw = bb;
            raw = fmaf(wc0, C.x, raw);
            raw = fmaf(wc1, C.y, raw);
            raw = fmaf(wc2, C.z, raw);
            raw = fmaf(wc3, qx - C.x, raw);
            raw = fmaf(wc4, qy - C.y, raw);
            raw = fmaf(wc5, qz - C.z, raw);
            se += raw;
            sqs = fmaf(raw, raw, sqs);
            hmax = fmaxf(hmax, raw);
            hmin = fminf(hmin, raw);

            // ---- owner-only tournament repair ----
            if ((win & 63) == lane) {
                const int slot = win >> 6;
                mask |= (1ull << slot);
                switch (slot >> 3) {
                    case 0: RECOMP(0); break;
                    case 1: RECOMP(1); break;
                    case 2: RECOMP(2); break;
                    case 3: RECOMP(3); break;
                    case 4: RECOMP(4); break;
                    case 5: RECOMP(5); break;
                    case 6: RECOMP(6); break;
                    default: RECOMP(7); break;
                }
                float bv = gv[0]; int bs = gs[0];
#pragma unroll
                for (int g2 = 1; g2 < 8; ++g2) if (gv[g2] < bv) { bv = gv[g2]; bs = gs[g2]; }
                dmin = bv; mmin = bs * 64 + lane;
            }
        }

        if (FAST) {
            rawmax[gq * 64 + lane] = hmax;
            rawmin[gq * 64 + lane] = hmin;
        }
    }

    // per-wave per-channel stats partials (deterministic, no atomics)
    partials[(bidx * 4 + wave) * 128 + lane] = se;
    partials[(bidx * 4 + wave) * 128 + 64 + lane] = sqs;
}

// ---------- kernel 3: reduce stats, finalize BN, fold affine ----------
__global__ void finalize_kernel(const float* __restrict__ partials,
                                const float* __restrict__ W,
                                const float* __restrict__ bias,
                                const float* __restrict__ gamma,
                                const float* __restrict__ beta,
                                float* __restrict__ ab,
                                float* __restrict__ w2) {
    __shared__ double red[8][64];
    const int t = threadIdx.x, c = t & 63, part = t >> 6;  // 256 threads
    double s = 0.0, q = 0.0;
    for (int i = part; i < NBLK * 4; i += 4) {
        s += (double)partials[i * 128 + c];
        q += (double)partials[i * 128 + 64 + c];
    }
    red[part][c] = s;
    red[4 + part][c] = q;
    __syncthreads();
    if (t < 64) {
        double ss = red[0][t] + red[1][t] + red[2][t] + red[3][t];
        double qq = red[4][t] + red[5][t] + red[6][t] + red[7][t];
        const double cnt = (double)P_TOT * KNN;
        double mean = ss / cnt;
        double var = qq / cnt - mean * mean;
        double a = (double)gamma[t] / sqrt(var + BN_EPS);
        float af = (float)a;
        float sh = (float)((double)beta[t] - mean * a);
        ab[t] = af;
        ab[64 + t] = sh;
#pragma unroll
        for (int f = 0; f < 6; ++f) w2[f * 64 + t] = W[f * 64 + t] * af;
        w2[384 + t] = fmaf(bias[t], af, sh);
    }
}

// ---------- kernel 4a (fast): elementwise BN+LeakyReLU on raw max/min ----------
__global__ __launch_bounds__(256) void final_kernel(const float* __restrict__ ab,
                                                    const float* __restrict__ rawmin,
                                                    float* __restrict__ out) {
    int i = blockIdx.x * 256 + threadIdx.x;
    int c = i & 63;
    float a = ab[c], sh = ab[64 + c];
    float va = fmaf(a, out[i], sh);       // out currently holds rawmax
    float vb = fmaf(a, rawmin[i], sh);
    va = va >= 0.f ? va : NEG_SLOPE * va;
    vb = vb >= 0.f ? vb : NEG_SLOPE * vb;
    out[i] = fmaxf(va, vb);               // monotone transform: covers a>=0 and a<0
}

// ---------- kernel 4b (fallback): gather + folded MLP + maxpool ----------
__global__ __launch_bounds__(256) void out_kernel(const float4* __restrict__ cloud,
                                                  const int* __restrict__ idxo,
                                                  const float* __restrict__ w2,
                                                  float* __restrict__ out) {
    const int t = threadIdx.x, c = t & 63;
    const int gp = blockIdx.x * 4 + (t >> 6);
    const int gb = gp & ~(NPTS - 1);
    const float wc0 = w2[c], wc1 = w2[64 + c], wc2 = w2[128 + c];
    const float wc3 = w2[192 + c], wc4 = w2[256 + c], wc5 = w2[320 + c];
    const float bc = w2[384 + c];
    const float4 Q = cloud[gp];
    float vmax = -INFINITY;
    for (int k = 0; k < KNN; ++k) {
        const int m = idxo[gp * KNN + k];
        const float4 C = cloud[gb + m];
        float h = bc;
        h = fmaf(wc0, C.x, h);
        h = fmaf(wc1, C.y, h);
        h = fmaf(wc2, C.z, h);
        h = fmaf(wc3, Q.x - C.x, h);
        h = fmaf(wc4, Q.y - C.y, h);
        h = fmaf(wc5, Q.z - C.z, h);
        h = h >= 0.f ? h : NEG_SLOPE * h;
        vmax = fmaxf(vmax, h);
    }
    out[gp * 64 + c] = vmax;
}

extern "C" void kernel_launch(void* const* d_in, const int* in_sizes, int n_in,
                              void* d_out, int out_size, void* d_ws, size_t ws_size,
                              hipStream_t stream) {
    const float* pcd   = (const float*)d_in[0];
    const float* W     = (const float*)d_in[1];
    const float* bias  = (const float*)d_in[2];
    const float* gamma = (const float*)d_in[3];
    const float* beta  = (const float*)d_in[4];

    float* wsf = (float*)d_ws;
    float4* cloud   = (float4*)(wsf + FO_CLOUD);
    float* partials = wsf + FO_PART;
    float* ab       = wsf + FO_AB;
    float* w2       = wsf + FO_W2;
    float* big      = wsf + FO_BIG;
    float* out      = (float*)d_out;

    const size_t need_fast = (size_t)FO_BIG * 4 + (size_t)P_TOT * 64 * 4 + 1024;
    const bool fast = ws_size >= need_fast;

    pack_kernel<<<P_TOT / 256, 256, 0, stream>>>(pcd, cloud);
    if (fast) {
        knn_kernel<true><<<NBLK, 256, 0, stream>>>(cloud, W, bias, partials, out, big, nullptr);
        finalize_kernel<<<1, 256, 0, stream>>>(partials, W, bias, gamma, beta, ab, w2);
        final_kernel<<<(P_TOT * 64) / 256, 256, 0, stream>>>(ab, big, out);
    } else {
        knn_kernel<false><<<NBLK, 256, 0, stream>>>(cloud, W, bias, partials, nullptr, nullptr, (int*)big);
        finalize_kernel<<<1, 256, 0, stream>>>(partials, W, bias, gamma, beta, ab, w2);
        out_kernel<<<P_TOT / 4, 256, 0, stream>>>(cloud, (int*)big, w2, out);
    }
}